// Round 6
// baseline (753.605 us; speedup 1.0000x reference)
//
#include <hip/hip_runtime.h>
#include <hip/hip_bf16.h>

#define NS 48
#define NV 10
#define NATT 78
#define HID 128
#define W1N 2304
#define W2N 480
#define W3N 100
#define W4N 480
#define WTOT 3364
#define NEDGE 50000
#define NNODE 10000
#define EPAD 50048       // 1564 * 32
#define EPSV 1e-5f
#define INV_SQRT3 0.57735026918962576f
#define NORM0 0.13130643285972254f   // 1/sqrt(58)
#define NORM1 0.13130643285972254f

// Repacked Bt2 column layout (tiles of 16 cols, 232 tiles = 3712 cols):
//  A: tiles   0..143  w1  c'=u*48+v
//  B: tiles 144..173  w4  c'=2884+u*48+v
//  C: tiles 174..221  w2  one u per tile, col=v (v<10 valid, rest zero-pad)
//  D: tiles 222..231  w3  one u per tile, col=v (v<10 valid)
#define CPAD2 3712
#define NT_A 144
#define NT_B 30
#define NT_C 48
#define NT_D 10
#define NPREP 58         // CPAD2/64 blocks for the prep role

using short8 = __attribute__((ext_vector_type(8))) short;
using f32x4  = __attribute__((ext_vector_type(4))) float;

// Compensated bf16: x ~= hi + lo, both bf16. GEMM = Ah*Bh + Ah*Bl + Al*Bh
// -> effective ~17-bit mantissa products, error ~1e-5 rel. Removes the
// precision knife-edge seen in rounds 2-5 (absmax 0.03..0.27 vs thr 0.141).
__device__ __forceinline__ unsigned short f2bf(float x) {
  union { float f; unsigned u; } v; v.f = x;
  unsigned r = v.u + 0x7fff + ((v.u >> 16) & 1);
  return (unsigned short)(r >> 16);
}
__device__ __forceinline__ float bf2f(unsigned short h) {
  union { unsigned u; float f; } v; v.u = (unsigned)h << 16;
  return v.f;
}

__device__ __forceinline__ int map_cp(int cp) {
  if (cp < 2304) return cp;                                       // w1
  if (cp < 2784) return 2884 + (cp - 2304);                       // w4
  if (cp < 3552) { int t = cp - 2784; int u = t >> 4, v = t & 15;
                   return (v < 10) ? (2304 + u * 10 + v) : -1; }  // w2
  { int t = cp - 3552; int u = t >> 4, v = t & 15;
    return (v < 10) ? (2784 + u * 10 + v) : -1; }                 // w3
}

// ---------------- K1: fused prep (blocks < NPREP) + fc1 (rest) ------------------
__global__ __launch_bounds__(256, 4) void k_prep_fc1(const float* __restrict__ w2,
                                                     const float* __restrict__ b2,
                                                     unsigned short* __restrict__ Bt2h,
                                                     unsigned short* __restrict__ Bt2l,
                                                     float* __restrict__ b2p,
                                                     const float* __restrict__ ea,
                                                     const float* __restrict__ w1,
                                                     const float* __restrict__ b1,
                                                     unsigned short* __restrict__ hbfh,
                                                     unsigned short* __restrict__ hbfl) {
  __shared__ union {
    struct { unsigned short Th[64][130]; unsigned short Tl[64][130]; } p;
    float sT[128][36];
  } sm;
  int tid = threadIdx.x;

  if (blockIdx.x < NPREP) {
    // ---- prep role: fc_w2 -> Bt2 hi/lo bf16 [CPAD2][128], coalesced ----
    int cp0 = blockIdx.x * 64;
    for (int i = tid; i < 64 * 128; i += 256) {
      int cp_l = i & 63, k = i >> 6;
      int c_src = map_cp(cp0 + cp_l);
      float val = (c_src >= 0) ? w2[(size_t)k * WTOT + c_src] : 0.f;
      unsigned short hi = f2bf(val);
      sm.p.Th[cp_l][k] = hi;
      sm.p.Tl[cp_l][k] = f2bf(val - bf2f(hi));
    }
    __syncthreads();
    for (int i = tid; i < 64 * 128; i += 256) {
      int k = i & 127, cp_l = i >> 7;
      Bt2h[(size_t)(cp0 + cp_l) * 128 + k] = sm.p.Th[cp_l][k];
      Bt2l[(size_t)(cp0 + cp_l) * 128 + k] = sm.p.Tl[cp_l][k];
    }
    if (tid < 64) {
      int cp = cp0 + tid;
      int c_src = map_cp(cp);
      b2p[cp] = (c_src >= 0) ? b2[c_src] : 0.f;
    }
    return;
  }

  // ---- fc1 role: h = relu(edge_attr @ fc_w1 + b1) -> bf16 hi/lo [EPAD][128] ----
  int e0 = (blockIdx.x - NPREP) * 32;
  for (int i = tid; i < 32 * 128; i += 256) {
    int el = i >> 7, k = i & 127;
    int e = e0 + el;
    sm.sT[k][el] = (e < NEDGE) ? ea[(size_t)e * 128 + k] : 0.f;
  }
  __syncthreads();
  int cg = tid & 31;
  int eg = tid >> 5;
  float acc[4][4] = {};
  #pragma unroll 8
  for (int k = 0; k < 128; ++k) {
    float4 a = *(const float4*)&sm.sT[k][eg * 4];
    float4 w = *(const float4*)&w1[k * 128 + cg * 4];
    float av[4] = {a.x, a.y, a.z, a.w};
    float wv[4] = {w.x, w.y, w.z, w.w};
    #pragma unroll
    for (int ii = 0; ii < 4; ++ii)
      #pragma unroll
      for (int jj = 0; jj < 4; ++jj)
        acc[ii][jj] += av[ii] * wv[jj];
  }
  float bb[4];
  #pragma unroll
  for (int jj = 0; jj < 4; ++jj) bb[jj] = b1[cg * 4 + jj];
  #pragma unroll
  for (int ii = 0; ii < 4; ++ii) {
    int e = e0 + eg * 4 + ii;
    bool val = e < NEDGE;
    unsigned short h4h[4], h4l[4];
    #pragma unroll
    for (int jj = 0; jj < 4; ++jj) {
      float r = val ? fmaxf(acc[ii][jj] + bb[jj], 0.f) : 0.f;
      h4h[jj] = f2bf(r);
      h4l[jj] = f2bf(r - bf2f(h4h[jj]));
    }
    uint2 pkh, pkl;
    pkh.x = (unsigned)h4h[0] | ((unsigned)h4h[1] << 16);
    pkh.y = (unsigned)h4h[2] | ((unsigned)h4h[3] << 16);
    pkl.x = (unsigned)h4l[0] | ((unsigned)h4l[1] << 16);
    pkl.y = (unsigned)h4l[2] | ((unsigned)h4l[3] << 16);
    *(uint2*)(hbfh + (size_t)e * 128 + cg * 4) = pkh;
    *(uint2*)(hbfl + (size_t)e * 128 + cg * 4) = pkl;
  }
}

// ---------------- K3: fused GEMM + tensor product, 4 waves split the tiles ------
// (256,3): VGPR cap ~170 — compensated GEMM needs ~130 live regs; a tighter
// bound caused catastrophic scratch spill in round 3 (VGPR=40, FETCH 496MB).
__global__ __launch_bounds__(256, 3) void k_tp(const unsigned short* __restrict__ hbfh,
                                               const unsigned short* __restrict__ hbfl,
                                               const unsigned short* __restrict__ Bt2h,
                                               const unsigned short* __restrict__ Bt2l,
                                               const float* __restrict__ b2p,
                                               const int* __restrict__ eidx,
                                               const float* __restrict__ node_attr,
                                               const float* __restrict__ esh,
                                               float* __restrict__ summed,
                                               float* __restrict__ cnt) {
  __shared__ float sF[32][49];
  __shared__ float vF[32][30];
  __shared__ float dotN[32][10];   // dot * INV_SQRT3 * NORM0
  __shared__ float p0F[32], q0F[32];
  __shared__ float sh1nF[32][3];
  __shared__ int   srcL[32], dstL[32];
  __shared__ float outAcc[32][80];

  int tid = threadIdx.x;           // 256 threads = 4 waves
  int e0 = blockIdx.x * 32;

  for (int i = tid; i < 32 * 80; i += 256) ((float*)outAcc)[i] = 0.f;

  float s1x = 0.f, s1y = 0.f, s1z = 0.f;
  if (tid < 32) {
    int eg = e0 + tid;
    bool val = eg < NEDGE;
    srcL[tid] = val ? eidx[eg] : -1;
    dstL[tid] = val ? eidx[NEDGE + eg] : -1;
    float sh0 = 0.f;
    if (val) {
      float4 s4 = *(const float4*)&esh[(size_t)eg * 4];
      sh0 = s4.x; s1x = s4.y; s1y = s4.z; s1z = s4.w;
    }
    p0F[tid] = sh0 * NORM0;
    q0F[tid] = sh0 * NORM1;
    sh1nF[tid][0] = s1x * NORM1; sh1nF[tid][1] = s1y * NORM1; sh1nF[tid][2] = s1z * NORM1;
  }
  __syncthreads();
  for (int i = tid; i < 32 * NATT; i += 256) {
    int el = i / NATT, a = i % NATT;
    int dst = dstL[el];
    float x = (dst >= 0) ? node_attr[(size_t)dst * NATT + a] : 0.f;
    if (a < NS) sF[el][a] = x; else vF[el][a - NS] = x;
  }
  __syncthreads();
  if (tid < 32) {
    #pragma unroll
    for (int u = 0; u < NV; ++u)
      dotN[tid][u] = (vF[tid][u*3] * s1x + vF[tid][u*3+1] * s1y + vF[tid][u*3+2] * s1z)
                     * (INV_SQRT3 * NORM0);
  }
  __syncthreads();

  int lane = tid & 63;
  int wave = tid >> 6;             // 0..3, tile-range split
  int quad = lane >> 4;
  int col  = lane & 15;
  int elq  = quad * 4;

  // A fragments hi/lo in registers: all 32 edges x K=128
  short8 aFh[2][4], aFl[2][4];
  {
    const short8* hph = (const short8*)hbfh;
    const short8* hpl = (const short8*)hbfl;
    #pragma unroll
    for (int mt = 0; mt < 2; ++mt) {
      size_t row = (size_t)(e0 + mt * 16 + col) * 16;
      #pragma unroll
      for (int ks = 0; ks < 4; ++ks) {
        aFh[mt][ks] = hph[row + ks * 4 + quad];
        aFl[mt][ks] = hpl[row + ks * 4 + quad];
      }
    }
  }

  const short8* bph = (const short8*)Bt2h;
  const short8* bpl = (const short8*)Bt2l;

  // Compensated tile: m = Ah*Bh + (Ah*Bl + Al*Bh), two independent MFMA chains
  auto do_tile = [&](int t, f32x4& m0, f32x4& m1) {
    size_t off = (size_t)(t * 16 + col) * 16 + quad;
    short8 bh[4], bl[4];
    #pragma unroll
    for (int ks = 0; ks < 4; ++ks) { bh[ks] = bph[off + ks * 4]; bl[ks] = bpl[off + ks * 4]; }
    f32x4 a0 = {0.f,0.f,0.f,0.f}, c0 = {0.f,0.f,0.f,0.f};
    f32x4 a1 = {0.f,0.f,0.f,0.f}, c1 = {0.f,0.f,0.f,0.f};
    #pragma unroll
    for (int ks = 0; ks < 4; ++ks) {
      a0 = __builtin_amdgcn_mfma_f32_16x16x32_bf16(aFh[0][ks], bh[ks], a0, 0, 0, 0);
      c0 = __builtin_amdgcn_mfma_f32_16x16x32_bf16(aFh[0][ks], bl[ks], c0, 0, 0, 0);
      c0 = __builtin_amdgcn_mfma_f32_16x16x32_bf16(aFl[0][ks], bh[ks], c0, 0, 0, 0);
      a1 = __builtin_amdgcn_mfma_f32_16x16x32_bf16(aFh[1][ks], bh[ks], a1, 0, 0, 0);
      c1 = __builtin_amdgcn_mfma_f32_16x16x32_bf16(aFh[1][ks], bl[ks], c1, 0, 0, 0);
      c1 = __builtin_amdgcn_mfma_f32_16x16x32_bf16(aFl[1][ks], bh[ks], c1, 0, 0, 0);
    }
    #pragma unroll
    for (int r = 0; r < 4; ++r) { m0[r] = a0[r] + c0[r]; m1[r] = a1[r] + c1[r]; }
  };

  // per-wave u-ranges
  int uA0 = wave * 12, uA1 = uA0 + 12;                  // regions A and C (48)
  int uB0 = (wave <= 2) ? wave * 3 : 8;                 // regions B and D (10): 3,3,2,2
  int uB1 = (wave < 2) ? uB0 + 3 : uB0 + 2;

  {
    float acc0[2][4][3] = {};   // out0[el][16j+col] partial; dies at flush below
    // ---- Region A: w1 ----
    #pragma unroll 1
    for (int u = uA0; u < uA1; ++u) {
      float sfac[2][4];
      #pragma unroll
      for (int mt = 0; mt < 2; ++mt)
        #pragma unroll
        for (int r = 0; r < 4; ++r)
          sfac[mt][r] = sF[mt * 16 + elq + r][u] * p0F[mt * 16 + elq + r];
      #pragma unroll
      for (int j = 0; j < 3; ++j) {
        int t = u * 3 + j;
        float b2c = b2p[t * 16 + col];
        f32x4 m0, m1;
        do_tile(t, m0, m1);
        #pragma unroll
        for (int r = 0; r < 4; ++r) {
          acc0[0][r][j] += (m0[r] + b2c) * sfac[0][r];
          acc0[1][r][j] += (m1[r] + b2c) * sfac[1][r];
        }
      }
    }
    // ---- Region B: w4 ----
    #pragma unroll 1
    for (int u = uB0; u < uB1; ++u) {
      float dfac[2][4];
      #pragma unroll
      for (int mt = 0; mt < 2; ++mt)
        #pragma unroll
        for (int r = 0; r < 4; ++r)
          dfac[mt][r] = dotN[mt * 16 + elq + r][u];
      #pragma unroll
      for (int j = 0; j < 3; ++j) {
        int t = NT_A + u * 3 + j;
        float b2c = b2p[t * 16 + col];
        f32x4 m0, m1;
        do_tile(t, m0, m1);
        #pragma unroll
        for (int r = 0; r < 4; ++r) {
          acc0[0][r][j] += (m0[r] + b2c) * dfac[0][r];
          acc0[1][r][j] += (m1[r] + b2c) * dfac[1][r];
        }
      }
    }
    // ---- Flush acc0 into LDS combiner (frees 24 VGPRs) ----
    #pragma unroll
    for (int mt = 0; mt < 2; ++mt)
      #pragma unroll
      for (int r = 0; r < 4; ++r)
        #pragma unroll
        for (int j = 0; j < 3; ++j)
          atomicAdd(&outAcc[mt * 16 + elq + r][j * 16 + col], acc0[mt][r][j]);
  }

  {
    float t1a[2][4] = {};       // sum_u w2[u,col]*s[u] partial (col<10)
    // ---- Region C: w2 (col = v) ----
    #pragma unroll 1
    for (int u = uA0; u < uA1; ++u) {
      int t = NT_A + NT_B + u;
      float b2c = b2p[t * 16 + col];
      float sc[2][4];
      #pragma unroll
      for (int mt = 0; mt < 2; ++mt)
        #pragma unroll
        for (int r = 0; r < 4; ++r)
          sc[mt][r] = sF[mt * 16 + elq + r][u];
      f32x4 m0, m1;
      do_tile(t, m0, m1);
      #pragma unroll
      for (int r = 0; r < 4; ++r) {
        t1a[0][r] += (m0[r] + b2c) * sc[0][r];
        t1a[1][r] += (m1[r] + b2c) * sc[1][r];
      }
    }
    if (col < 10) {
      #pragma unroll
      for (int mt = 0; mt < 2; ++mt)
        #pragma unroll
        for (int r = 0; r < 4; ++r) {
          int el = mt * 16 + elq + r;
          #pragma unroll
          for (int i = 0; i < 3; ++i)
            atomicAdd(&outAcc[el][NS + col * 3 + i], t1a[mt][r] * sh1nF[el][i]);
        }
    }
  }

  {
    float t3a[2][4][3] = {};    // sum_u w3[u,col]*v[u][i] partial
    // ---- Region D: w3 (col = v) ----
    #pragma unroll 1
    for (int u = uB0; u < uB1; ++u) {
      int t = NT_A + NT_B + NT_C + u;
      float b2c = b2p[t * 16 + col];
      f32x4 m0, m1;
      do_tile(t, m0, m1);
      #pragma unroll
      for (int mt = 0; mt < 2; ++mt)
        #pragma unroll
        for (int r = 0; r < 4; ++r) {
          float w = (mt == 0 ? m0[r] : m1[r]) + b2c;
          int el = mt * 16 + elq + r;
          #pragma unroll
          for (int i = 0; i < 3; ++i)
            t3a[mt][r][i] += w * vF[el][u * 3 + i];
        }
    }
    if (col < 10) {
      #pragma unroll
      for (int mt = 0; mt < 2; ++mt)
        #pragma unroll
        for (int r = 0; r < 4; ++r) {
          int el = mt * 16 + elq + r;
          float q0 = q0F[el];
          #pragma unroll
          for (int i = 0; i < 3; ++i)
            atomicAdd(&outAcc[el][NS + col * 3 + i], t3a[mt][r][i] * q0);
        }
    }
  }
  __syncthreads();

  // ---- Flush: LDS -> global atomics ----
  for (int i = tid; i < 32 * NATT; i += 256) {
    int el = i / NATT, oi = i % NATT;
    int src = srcL[el];
    if (src >= 0) atomicAdd(&summed[(size_t)src * NATT + oi], outAcc[el][oi]);
  }
  if (tid < 32 && srcL[tid] >= 0) atomicAdd(&cnt[srcL[tid]], 1.0f);
}

// ---------------- K4: mean over segment + residual, accumulate BN stats ---------
__global__ __launch_bounds__(256) void k_node(const float* __restrict__ summed,
                                              const float* __restrict__ cnt,
                                              const float* __restrict__ node_attr,
                                              float* __restrict__ outp,
                                              float* __restrict__ stats) {
  __shared__ float ls[NS], lq[NS], lv[NV];
  int tid = threadIdx.x;
  if (tid < NS) { ls[tid] = 0.f; lq[tid] = 0.f; }
  if (tid < NV) lv[tid] = 0.f;
  __syncthreads();
  int i = blockIdx.x * 256 + tid;
  if (i < NNODE * NATT) {
    int row = i / NATT, colc = i % NATT;
    float x = summed[i] / fmaxf(cnt[row], 1.f) + node_attr[i];
    outp[i] = x;
    if (colc < NS) { atomicAdd(&ls[colc], x); atomicAdd(&lq[colc], x * x); }
    else           { atomicAdd(&lv[(colc - NS) / 3], x * x); }
  }
  __syncthreads();
  if (tid < NS) { atomicAdd(&stats[tid], ls[tid]); atomicAdd(&stats[NS + tid], lq[tid]); }
  if (tid < NV) atomicAdd(&stats[96 + tid], lv[tid]);
}

// ---------------- K5: batch norm apply ------------------------------------------
__global__ __launch_bounds__(256) void k_bn(const float* __restrict__ outp,
                                            const float* __restrict__ stats,
                                            const float* __restrict__ bnw,
                                            const float* __restrict__ bnb,
                                            float* __restrict__ out) {
  int i = blockIdx.x * 256 + threadIdx.x;
  if (i >= NNODE * NATT) return;
  int colc = i % NATT;
  float x = outp[i];
  float r;
  if (colc < NS) {
    float mean = stats[colc] * (1.f / NNODE);
    float var  = stats[NS + colc] * (1.f / NNODE) - mean * mean;
    r = (x - mean) * rsqrtf(var + EPSV) * bnw[colc] + bnb[colc];
  } else {
    int u = (colc - NS) / 3;
    float vn = stats[96 + u] * (1.f / (3.f * NNODE));
    r = x * rsqrtf(vn + EPSV) * bnw[NS + u];
  }
  out[i] = r;
}

extern "C" void kernel_launch(void* const* d_in, const int* in_sizes, int n_in,
                              void* d_out, int out_size, void* d_ws, size_t ws_size,
                              hipStream_t stream) {
  const float* node_attr = (const float*)d_in[0];
  const int*   eidx      = (const int*)d_in[1];
  const float* edge_attr = (const float*)d_in[2];
  const float* esh       = (const float*)d_in[3];
  const float* fw1       = (const float*)d_in[4];
  const float* fb1       = (const float*)d_in[5];
  const float* fw2       = (const float*)d_in[6];
  const float* fb2       = (const float*)d_in[7];
  const float* bnw       = (const float*)d_in[8];
  const float* bnb       = (const float*)d_in[9];
  float* out = (float*)d_out;

  char* ws = (char*)d_ws;
  // layout (bytes):
  //   Bt2h   @ 0        : CPAD2*128*2 =    950,272
  //   Bt2l   @ 950272   : CPAD2*128*2 =    950,272
  //   b2p    @ 1900544  : CPAD2*4     =     14,848
  //   hbfh   @ 1915392  : EPAD*128*2  = 12,812,288
  //   hbfl   @ 14727680 : EPAD*128*2  = 12,812,288
  //   summed @ 27539968 : N*78*4      =  3,120,000
  //   cnt    @ 30659968 : N*4         =     40,000
  //   stats  @ 30699968 : 128*4       =        512
  //   outp   @ 30700480 : N*78*4      =  3,120,000   (end 33,820,480)
  unsigned short* Bt2h   = (unsigned short*)(ws + 0);
  unsigned short* Bt2l   = (unsigned short*)(ws + 950272);
  float*          b2p    = (float*)(ws + 1900544);
  unsigned short* hbfh   = (unsigned short*)(ws + 1915392);
  unsigned short* hbfl   = (unsigned short*)(ws + 14727680);
  float*          summed = (float*)(ws + 27539968);
  float*          cnt    = (float*)(ws + 30659968);
  float*          stats  = (float*)(ws + 30699968);
  float*          outp   = (float*)(ws + 30700480);

  hipMemsetAsync(ws + 27539968, 0, 3120000 + 40000 + 512, stream);

  k_prep_fc1<<<NPREP + EPAD / 32, 256, 0, stream>>>(fw2, fb2, Bt2h, Bt2l, b2p,
                                                    edge_attr, fw1, fb1, hbfh, hbfl);
  k_tp<<<EPAD / 32, 256, 0, stream>>>(hbfh, hbfl, Bt2h, Bt2l, b2p,
                                      eidx, node_attr, esh, summed, cnt);
  int nelem_blocks = (NNODE * NATT + 255) / 256;
  k_node<<<nelem_blocks, 256, 0, stream>>>(summed, cnt, node_attr, outp, stats);
  k_bn<<<nelem_blocks, 256, 0, stream>>>(outp, stats, bnw, bnb, out);
}